// Round 5
// baseline (179.988 us; speedup 1.0000x reference)
//
#include <hip/hip_runtime.h>
#include <hip/hip_bf16.h>
#include <cstdint>
#include <math.h>

// Shapes: B=256, P=128, K=512, HE=1024, HF=512 (2HF=1024), D=2560, HID=64
// Outputs: embeddings (256,1,1536) then weights (256,128), fp32, flat-concat.
//
// R4 structure (post-mortem of R3 split: K2 keys re-read was a net loss):
//   K0: repack W1k -> w1kt bf16 [64][512] K-major, W1qf -> paired-bf16 words
//       w1qfp[1024][64] (word = (bf16(d+1)<<16)|bf16(d)).
//   K1: ONE fused kernel per batch: keys staging (HBM) interleaved with proj
//       GEMV (L2-hot w1qfp) so proj latency hides under keys' ~900cy HBM
//       round-trips; then MFMA scores -> softmax -> context -> outputs.

typedef __bf16 bf16;
typedef __attribute__((ext_vector_type(8))) __bf16 bf16x8;
typedef __attribute__((ext_vector_type(4))) __bf16 bf16x4;
typedef __attribute__((ext_vector_type(4))) float f32x4;

#define NB 256
#define NP 128
#define NK 512
#define SKLD 520   // keys LDS row stride (bf16): 1040B/row -> 2-way bank alias (free)
#define SK_BYTES (NP * SKLD * 2)                  // 133120
// + scores[128] + wts[128] + projpart[4][64] + w2l[64]
#define SMEM_BYTES (SK_BYTES + 128*4 + 128*4 + 256*4 + 64*4)  // 135424

// ---------------- K0: weight repack ----------------
// blocks 0..15 : w1kt[h][k] = bf16(W1[k*64+h])  (LDS transpose, 32 k-rows each)
// blocks 16..47: w1qfp[dp*64+h] = pack(bf16(W1[(512+2dp)*64+h]), bf16(W1[(513+2dp)*64+h]))
__global__ __launch_bounds__(256) void k0_repack(
    const float* __restrict__ W1, bf16* __restrict__ w1kt,
    uint32_t* __restrict__ w1qfp)
{
    const int blk = blockIdx.x;
    const int t = threadIdx.x;
    if (blk < 16) {
        __shared__ float s[32][65];
        const int k0 = blk * 32;
#pragma unroll
        for (int i = 0; i < 8; i++) {
            const int idx = t + 256 * i;
            const int k = idx >> 6, h = idx & 63;
            s[k][h] = W1[(size_t)(k0 + k) * 64 + h];
        }
        __syncthreads();
#pragma unroll
        for (int i = 0; i < 8; i++) {
            const int idx = t + 256 * i;
            const int h = idx >> 5, kk = idx & 31;
            w1kt[(size_t)h * 512 + k0 + kk] = (bf16)s[kk][h];
        }
    } else {
        const int jj = blk - 16;                 // 0..31, covers dp [32jj,32jj+32)
#pragma unroll
        for (int i = 0; i < 8; i++) {
            const int idx = t + 256 * i;         // 0..2047
            const int dpl = idx >> 6, h = idx & 63;
            const int dp = jj * 32 + dpl;
            const float r0 = W1[(size_t)(512 + 2 * dp) * 64 + h];
            const float r1 = W1[(size_t)(513 + 2 * dp) * 64 + h];
            const uint32_t b0 = (uint32_t)__builtin_bit_cast(unsigned short, (bf16)r0);
            const uint32_t b1 = (uint32_t)__builtin_bit_cast(unsigned short, (bf16)r1);
            w1qfp[(size_t)dp * 64 + h] = (b1 << 16) | b0;
        }
    }
}

// ---------------- K1: fused attention, one block per batch ----------------
__global__ __launch_bounds__(256, 1) void attn_kernel(
    const float* __restrict__ keys, const float* __restrict__ query,
    const float* __restrict__ frame, const int* __restrict__ mask,
    const float* __restrict__ W2, const bf16* __restrict__ w1kt,
    const uint32_t* __restrict__ w1qfp, float* __restrict__ out)
{
    extern __shared__ char smem[];
    bf16* sk      = (bf16*)smem;                  // [128][520] bf16
    float* scores = (float*)(smem + SK_BYTES);    // [128]
    float* wts    = scores + 128;                 // [128]
    float* pp     = wts + 128;                    // [4][64] proj partials
    float* w2l    = pp + 256;                     // [64]

    const int b = blockIdx.x;
    const int t = threadIdx.x;

    if (t < 64) w2l[t] = W2[t];

    // ---- phase A: keys staging (HBM) interleaved with proj GEMV (L2) ----
    // proj: thread (g = wave, h = lane) accumulates d in [512g, 512g+512)
    // from paired-bf16 words; src (query/frame) reads are wave-uniform -> SMEM.
    const float* kb = keys + (size_t)b * (NP * NK);
    const int rowadd = t >> 7;             // 0/1
    const int c0 = (t & 127) * 4;
    const int g = t >> 6;
    const int h = t & 63;
    const float2* s2 = (const float2*)((g < 2 ? query : frame)
                                       + (size_t)b * 1024 + (g & 1) * 512);
    const uint32_t* wp = w1qfp + (size_t)(g * 256) * 64 + h;   // + dd*64

    float acc = 0.f;
#pragma unroll
    for (int j = 0; j < 4; j++) {
        float4 kv[16];
#pragma unroll
        for (int ii = 0; ii < 16; ii++)
            kv[ii] = *(const float4*)(kb + (size_t)(j * 16 + ii) * 1024 + t * 4);
#pragma unroll 16
        for (int dd = 0; dd < 64; dd++) {
            const int d = j * 64 + dd;
            const uint32_t wv = wp[(size_t)d * 64];
            const float2 sv = s2[d];
            acc += sv.x * __uint_as_float(wv << 16);
            acc += sv.y * __uint_as_float(wv & 0xffff0000u);
        }
#pragma unroll
        for (int ii = 0; ii < 16; ii++) {
            bf16x4 bv;
            bv[0] = (bf16)kv[ii].x; bv[1] = (bf16)kv[ii].y;
            bv[2] = (bf16)kv[ii].z; bv[3] = (bf16)kv[ii].w;
            *(bf16x4*)(sk + (size_t)(2 * (j * 16 + ii) + rowadd) * SKLD + c0) = bv;
        }
    }
    pp[g * 64 + h] = acc;
    __syncthreads();

    // ---- GEMM: C[p][h] = keys_bf16 @ W1k_bf16 via mfma_f32_16x16x32_bf16 ----
    // wave w owns p in [32w,32w+32) (2 M-tiles), all 4 N-tiles (h=0..63)
    const int w = t >> 6;
    const int lane = t & 63;
    const int m = lane & 15;       // C col (h within tile)
    const int q = lane >> 4;       // C row = q*4 + r
    const int pw = w * 32;

    f32x4 acc2[2][4];
#pragma unroll
    for (int a = 0; a < 2; a++)
#pragma unroll
        for (int n = 0; n < 4; n++) acc2[a][n] = (f32x4){0.f, 0.f, 0.f, 0.f};

    for (int kk = 0; kk < 16; kk++) {
        const int k0 = kk * 32 + q * 8;
        const bf16x8 A0 = *(const bf16x8*)(sk + (pw + m) * SKLD + k0);
        const bf16x8 A1 = *(const bf16x8*)(sk + (pw + 16 + m) * SKLD + k0);
#pragma unroll
        for (int nt = 0; nt < 4; nt++) {
            const bf16x8 Bf = *(const bf16x8*)(w1kt + (size_t)(nt * 16 + m) * 512 + k0);
            acc2[0][nt] = __builtin_amdgcn_mfma_f32_16x16x32_bf16(A0, Bf, acc2[0][nt], 0, 0, 0);
            acc2[1][nt] = __builtin_amdgcn_mfma_f32_16x16x32_bf16(A1, Bf, acc2[1][nt], 0, 0, 0);
        }
    }

    // ---- epilogue: score[p] = sum_h relu(C[p][h] + proj[h]) * W2[h] ----
#pragma unroll
    for (int mt = 0; mt < 2; mt++) {
        float p0 = 0.f, p1 = 0.f, p2 = 0.f, p3 = 0.f;
#pragma unroll
        for (int nt = 0; nt < 4; nt++) {
            const int hh = nt * 16 + m;
            const float pv = pp[hh] + pp[64 + hh] + pp[128 + hh] + pp[192 + hh];
            const float wv = w2l[hh];
            const f32x4 c = acc2[mt][nt];
            p0 += fmaxf(c[0] + pv, 0.f) * wv;
            p1 += fmaxf(c[1] + pv, 0.f) * wv;
            p2 += fmaxf(c[2] + pv, 0.f) * wv;
            p3 += fmaxf(c[3] + pv, 0.f) * wv;
        }
#pragma unroll
        for (int off = 1; off < 16; off <<= 1) {
            p0 += __shfl_xor(p0, off);
            p1 += __shfl_xor(p1, off);
            p2 += __shfl_xor(p2, off);
            p3 += __shfl_xor(p3, off);
        }
        if (m == 0) {
            const int pbase = pw + mt * 16 + q * 4;
            scores[pbase + 0] = p0; scores[pbase + 1] = p1;
            scores[pbase + 2] = p2; scores[pbase + 3] = p3;
        }
    }
    __syncthreads();

    // ---- masked softmax over 128 scores (wave 0), write weights ----
    if (w == 0) {
        const int pa = lane, pb = lane + 64;
        float s0 = (mask[b * 128 + pa] == 0) ? -INFINITY : scores[pa];
        float s1 = (mask[b * 128 + pb] == 0) ? -INFINITY : scores[pb];
        float mx = fmaxf(s0, s1);
#pragma unroll
        for (int off = 32; off; off >>= 1) mx = fmaxf(mx, __shfl_xor(mx, off));
        float e0 = __expf(s0 - mx), e1 = __expf(s1 - mx);
        float sum = e0 + e1;
#pragma unroll
        for (int off = 32; off; off >>= 1) sum += __shfl_xor(sum, off);
        const float inv = 1.0f / sum;
        e0 *= inv; e1 *= inv;
        wts[pa] = e0; wts[pb] = e1;
        float* wout = out + (size_t)NB * 1536;
        wout[b * 128 + pa] = e0;
        wout[b * 128 + pb] = e1;
    }
    __syncthreads();

    // ---- context[k] = sum_p w[p]*keys[p][k]; thread owns cols 2t, 2t+1 ----
    {
        float a0 = 0.f, a1 = 0.f;
        const int c = 2 * t;
#pragma unroll 8
        for (int p = 0; p < 128; p++) {
            const float wv = wts[p];
            const uint32_t uv = *(const uint32_t*)(sk + p * SKLD + c);
            a0 += wv * __uint_as_float(uv << 16);
            a1 += wv * __uint_as_float(uv & 0xffff0000u);
        }
        out[(size_t)b * 1536 + c] = a0;
        out[(size_t)b * 1536 + c + 1] = a1;
    }
    // ---- frame passthrough: embeddings[:, 512:1536] = frameLSTM_h ----
    {
        const float4 fv = *(const float4*)(frame + (size_t)b * 1024 + t * 4);
        *(float4*)(out + (size_t)b * 1536 + 512 + t * 4) = fv;
    }
}

extern "C" void kernel_launch(void* const* d_in, const int* in_sizes, int n_in,
                              void* d_out, int out_size, void* d_ws, size_t ws_size,
                              hipStream_t stream) {
    const float* query = (const float*)d_in[0];
    const float* keys  = (const float*)d_in[1];
    const float* frame = (const float*)d_in[2];
    const int*   mask  = (const int*)d_in[3];
    const float* W1    = (const float*)d_in[4];
    const float* W2    = (const float*)d_in[5];
    float* out = (float*)d_out;

    // ws: [0,64K) w1kt bf16 [64][512]; [64K,320K) w1qfp uint32 [1024][64]
    bf16*     w1kt  = (bf16*)d_ws;
    uint32_t* w1qfp = (uint32_t*)((char*)d_ws + (64 << 10));

    hipFuncSetAttribute((const void*)attn_kernel,
                        hipFuncAttributeMaxDynamicSharedMemorySize, SMEM_BYTES);

    k0_repack<<<48, 256, 0, stream>>>(W1, w1kt, w1qfp);
    attn_kernel<<<256, 256, SMEM_BYTES, stream>>>(keys, query, frame, mask, W2,
                                                  w1kt, w1qfp, out);
}

// Round 6
// 159.242 us; speedup vs baseline: 1.1303x; 1.1303x over previous
//
#include <hip/hip_runtime.h>
#include <hip/hip_bf16.h>
#include <cstdint>
#include <math.h>

// Shapes: B=256, P=128, K=512, HE=1024, HF=512 (2HF=1024), D=2560, HID=64
// Outputs: embeddings (256,1,1536) then weights (256,128), fp32, flat-concat.
//
// R5: prep (proj split-4 + W1k repack + zero flags/context) ->
//     k1 fused attention with 2 blocks per batch (2 blocks/CU), pair-sync via
//     device-scope flag; context partials from each block's LDS keys half,
//     atomicAdd into pre-zeroed out. ONE keys read total.
// R4 lesson: never interleave dependent L2-load chains with HBM staging —
// vmcnt is one queue; the waits de-pipeline everything.

typedef __bf16 bf16;
typedef __attribute__((ext_vector_type(8))) __bf16 bf16x8;
typedef __attribute__((ext_vector_type(4))) __bf16 bf16x4;
typedef __attribute__((ext_vector_type(4))) float f32x4;

#define NB 256
#define NP 128
#define NK 512
#define SKLD 520   // keys LDS row stride (bf16): 1040B/row -> 2-way bank alias (free)
#define K1_SK_BYTES (64 * SKLD * 2)                       // 66560
#define K1_SMEM (K1_SK_BYTES + 64*4 + 64*4 + 128*4)       // +projl+w2l+wts = 67584 (2 blocks/CU)

// ---------------- prep: proj GEMV (4 blocks/batch) + repack + zero ----------
// blocks 0..1023   : proj_part[q4][b][h], 128-deep chains
// blocks 1024..1039: w1kt transpose (32 k-rows each) + zero flags (j==0) +
//                    zero context region of out (16 batches each)
__global__ __launch_bounds__(256) void prep_kernel(
    const float* __restrict__ query, const float* __restrict__ frame,
    const float* __restrict__ W1, bf16* __restrict__ w1kt,
    float* __restrict__ proj_part, int* __restrict__ flags,
    float* __restrict__ out)
{
    const int blk = blockIdx.x;
    const int t = threadIdx.x;
    if (blk < 1024) {
        __shared__ float part[4][64];
        const int b = blk >> 2;
        const int q4 = blk & 3;              // d-range [512*q4, 512*q4+512) of concat(query,frame)
        const int h = t & 63;
        const int g = t >> 6;                // 4 chunks of 128 d's
        const float* src = (q4 < 2 ? query : frame) + (size_t)b * 1024 + (q4 & 1) * 512 + g * 128;
        const float* wrow = W1 + (size_t)(512 + q4 * 512 + g * 128) * 64 + h;
        float acc = 0.f;
#pragma unroll 8
        for (int dd = 0; dd < 128; dd++)
            acc += src[dd] * wrow[(size_t)dd * 64];
        part[g][h] = acc;
        __syncthreads();
        if (t < 64)
            proj_part[((size_t)q4 * NB + b) * 64 + t] =
                part[0][t] + part[1][t] + part[2][t] + part[3][t];
    } else {
        __shared__ float s[32][65];
        const int j = blk - 1024;            // 0..15
        const int k0 = j * 32;
#pragma unroll
        for (int i = 0; i < 8; i++) {
            const int idx = t + 256 * i;
            const int k = idx >> 6, h = idx & 63;
            s[k][h] = W1[(size_t)(k0 + k) * 64 + h];
        }
        // zero pair-flags (block j==0) and context region of out (16 batches/block)
        if (j == 0) flags[t] = 0;
#pragma unroll
        for (int bb = 0; bb < 16; bb++) {
            const int b = j * 16 + bb;
            out[(size_t)b * 1536 + t] = 0.f;
            out[(size_t)b * 1536 + 256 + t] = 0.f;
        }
        __syncthreads();
#pragma unroll
        for (int i = 0; i < 8; i++) {
            const int idx = t + 256 * i;
            const int h = idx >> 5, kk = idx & 31;
            w1kt[(size_t)h * 512 + k0 + kk] = (bf16)s[kk][h];
        }
    }
}

// ---------------- k1: fused attention, block = (batch, P-half) --------------
__global__ __launch_bounds__(256, 2) void k1_attn(
    const float* __restrict__ keys, const float* __restrict__ frame,
    const int* __restrict__ mask, const float* __restrict__ W2,
    const bf16* __restrict__ w1kt, const float* __restrict__ proj_part,
    float* __restrict__ scores_ws, int* __restrict__ flags,
    float* __restrict__ out)
{
    extern __shared__ char smem[];
    bf16* sk     = (bf16*)smem;                    // [64][520]
    float* projl = (float*)(smem + K1_SK_BYTES);   // [64]
    float* w2l   = projl + 64;                     // [64]
    float* wts   = w2l + 64;                       // [128] (masked scores, then weights)

    const int b    = blockIdx.x >> 1;
    const int half = blockIdx.x & 1;
    const int t = threadIdx.x;

    if (t < 64)
        projl[t] = proj_part[(size_t)b * 64 + t]
                 + proj_part[((size_t)NB + b) * 64 + t]
                 + proj_part[((size_t)2 * NB + b) * 64 + t]
                 + proj_part[((size_t)3 * NB + b) * 64 + t];
    else if (t < 128) w2l[t - 64] = W2[t - 64];

    // ---- stage my 64 key rows (128KB fp32, HBM) -> LDS bf16, coalesced ----
    const float* kb = keys + (size_t)b * (NP * NK) + (size_t)half * 64 * NK;
    {
        const int rowadd = t >> 7;
        const int c0 = (t & 127) * 4;
#pragma unroll 8
        for (int i = 0; i < 32; i++) {
            const float4 v = *(const float4*)(kb + (size_t)i * 1024 + t * 4);
            bf16x4 bv;
            bv[0] = (bf16)v.x; bv[1] = (bf16)v.y; bv[2] = (bf16)v.z; bv[3] = (bf16)v.w;
            *(bf16x4*)(sk + (2 * i + rowadd) * SKLD + c0) = bv;
        }
    }
    __syncthreads();

    // ---- GEMM: wave w owns rows [16w,16w+16); C col=h(lane&15), row=q*4+r ----
    const int w = t >> 6;
    const int lane = t & 63;
    const int m = lane & 15;
    const int q = lane >> 4;

    const bf16* bbase = w1kt + (size_t)m * 512 + q * 8;  // + nt*16*512 + kk*32
    bf16x8 Bc[4], Bn[4];
#pragma unroll
    for (int nt = 0; nt < 4; nt++) Bc[nt] = *(const bf16x8*)(bbase + nt * 8192);
#pragma unroll
    for (int nt = 0; nt < 4; nt++) Bn[nt] = *(const bf16x8*)(bbase + nt * 8192 + 32);

    f32x4 acc[4];
#pragma unroll
    for (int nt = 0; nt < 4; nt++) acc[nt] = (f32x4){0.f, 0.f, 0.f, 0.f};

#pragma unroll
    for (int kk = 0; kk < 16; kk++) {
        const bf16x8 A = *(const bf16x8*)(sk + (w * 16 + m) * SKLD + kk * 32 + q * 8);
        bf16x8 Bf[4];
#pragma unroll
        for (int nt = 0; nt < 4; nt++) Bf[nt] = Bc[nt];
#pragma unroll
        for (int nt = 0; nt < 4; nt++) Bc[nt] = Bn[nt];
        if (kk < 14) {
#pragma unroll
            for (int nt = 0; nt < 4; nt++)
                Bn[nt] = *(const bf16x8*)(bbase + nt * 8192 + (kk + 2) * 32);
        }
#pragma unroll
        for (int nt = 0; nt < 4; nt++)
            acc[nt] = __builtin_amdgcn_mfma_f32_16x16x32_bf16(A, Bf[nt], acc[nt], 0, 0, 0);
    }

    // ---- epilogue: raw score[p] = sum_h relu(C+proj)*W2 -> ws (agent scope) ----
    float pr[4] = {0.f, 0.f, 0.f, 0.f};
#pragma unroll
    for (int nt = 0; nt < 4; nt++) {
        const int h = nt * 16 + m;
        const float pv = projl[h];
        const float wv = w2l[h];
#pragma unroll
        for (int r = 0; r < 4; r++)
            pr[r] += fmaxf(acc[nt][r] + pv, 0.f) * wv;
    }
#pragma unroll
    for (int off = 1; off < 16; off <<= 1) {
#pragma unroll
        for (int r = 0; r < 4; r++) pr[r] += __shfl_xor(pr[r], off);
    }
    if (m == 0) {
        const int base = b * 128 + half * 64 + w * 16 + q * 4;
#pragma unroll
        for (int r = 0; r < 4; r++)
            __hip_atomic_store(&scores_ws[base + r], pr[r],
                               __ATOMIC_RELAXED, __HIP_MEMORY_SCOPE_AGENT);
    }
    __threadfence();
    __syncthreads();

    // ---- pair handshake: wait until both halves published their scores ----
    if (t == 0) {
        atomicAdd(&flags[b], 1);
        while (__hip_atomic_load(&flags[b], __ATOMIC_ACQUIRE,
                                 __HIP_MEMORY_SCOPE_AGENT) < 2)
            __builtin_amdgcn_s_sleep(1);
    }
    __syncthreads();

    // ---- full masked softmax (both blocks compute; half==0 writes weights) ----
    if (t < 128) {
        const float raw = __hip_atomic_load(&scores_ws[b * 128 + t],
                                            __ATOMIC_RELAXED, __HIP_MEMORY_SCOPE_AGENT);
        wts[t] = (mask[b * 128 + t] == 0) ? -INFINITY : raw;
    }
    __syncthreads();
    if (w == 0) {
        float s0 = wts[lane], s1 = wts[lane + 64];
        float mx = fmaxf(s0, s1);
#pragma unroll
        for (int off = 32; off; off >>= 1) mx = fmaxf(mx, __shfl_xor(mx, off));
        float e0 = __expf(s0 - mx), e1 = __expf(s1 - mx);
        float sum = e0 + e1;
#pragma unroll
        for (int off = 32; off; off >>= 1) sum += __shfl_xor(sum, off);
        const float inv = 1.0f / sum;
        wts[lane] = e0 * inv;
        wts[lane + 64] = e1 * inv;
    }
    __syncthreads();

    if (half == 0 && t < 128)
        out[(size_t)NB * 1536 + b * 128 + t] = wts[t];

    // ---- partial context from my LDS half: cols 2t,2t+1 over 64 rows ----
    {
        float a0 = 0.f, a1 = 0.f;
        const int c = 2 * t;
#pragma unroll 8
        for (int r = 0; r < 64; r++) {
            const float wv = wts[half * 64 + r];
            const uint32_t uv = *(const uint32_t*)(sk + r * SKLD + c);
            a0 += wv * __uint_as_float(uv << 16);
            a1 += wv * __uint_as_float(uv & 0xffff0000u);
        }
        atomicAdd(&out[(size_t)b * 1536 + c], a0);
        atomicAdd(&out[(size_t)b * 1536 + c + 1], a1);
    }

    // ---- frame passthrough (half==1 block): embeddings[:,512:1536] ----
    if (half == 1) {
        const float4 fv = *(const float4*)(frame + (size_t)b * 1024 + t * 4);
        *(float4*)(out + (size_t)b * 1536 + 512 + t * 4) = fv;
    }
}

extern "C" void kernel_launch(void* const* d_in, const int* in_sizes, int n_in,
                              void* d_out, int out_size, void* d_ws, size_t ws_size,
                              hipStream_t stream) {
    const float* query = (const float*)d_in[0];
    const float* keys  = (const float*)d_in[1];
    const float* frame = (const float*)d_in[2];
    const int*   mask  = (const int*)d_in[3];
    const float* W1    = (const float*)d_in[4];
    const float* W2    = (const float*)d_in[5];
    float* out = (float*)d_out;

    // ws: [0,64K) w1kt bf16 [64][512]; [64K,320K) proj_part fp32 [4][256][64];
    //     [320K,321K) flags int[256]; [324K,452K) scores_ws fp32 [256][128]
    bf16*  w1kt      = (bf16*)d_ws;
    float* proj_part = (float*)((char*)d_ws + (64 << 10));
    int*   flags     = (int*)((char*)d_ws + (320 << 10));
    float* scores_ws = (float*)((char*)d_ws + (324 << 10));

    hipFuncSetAttribute((const void*)k1_attn,
                        hipFuncAttributeMaxDynamicSharedMemorySize, K1_SMEM);

    prep_kernel<<<1040, 256, 0, stream>>>(query, frame, W1, w1kt, proj_part, flags, out);
    k1_attn<<<512, 256, K1_SMEM, stream>>>(keys, frame, mask, W2, w1kt, proj_part,
                                           scores_ws, flags, out);
}

// Round 7
// 123.473 us; speedup vs baseline: 1.4577x; 1.2897x over previous
//
#include <hip/hip_runtime.h>
#include <hip/hip_bf16.h>
#include <cstdint>
#include <math.h>

// Shapes: B=256, P=128, K=512, HE=1024, HF=512 (2HF=1024), D=2560, HID=64
// Outputs: embeddings (256,1,1536) then weights (256,128), fp32, flat-concat.
//
// R6 = measured-best structure (R3 prep + R2 fused attn) + explicit register
// double-buffers for keys staging and B-fragments.
// Ledger: R2 fused attn 39us | R3 split 44 | R5 interleave 95 | R6 handshake 65.
// Lessons: no inter-block coupling; phases dependency-homogeneous (vmcnt is one
// queue); pipelining must be explicit register arrays, not pragmas.

typedef __bf16 bf16;
typedef __attribute__((ext_vector_type(8))) __bf16 bf16x8;
typedef __attribute__((ext_vector_type(4))) __bf16 bf16x4;
typedef __attribute__((ext_vector_type(4))) float f32x4;

#define NB 256
#define NP 128
#define NK 512
#define SKLD 520   // keys LDS row stride (bf16): 1040B/row -> 2-way bank alias (free)
#define SK_BYTES (NP * SKLD * 2)                  // 133120
#define SMEM_BYTES (SK_BYTES + 128*4 + 128*4 + 64*4 + 64*4)  // +scores+wts+proj+w2

// ---------------- prep: proj GEMV (4 blocks/batch) + W1k repack -------------
// blocks 0..1023   : proj_part[q4][b][h], 128-deep chains (latency-spread)
// blocks 1024..1039: w1kt[h][k] = bf16(W1[k*64+h]) via LDS transpose
__global__ __launch_bounds__(256) void prep_kernel(
    const float* __restrict__ query, const float* __restrict__ frame,
    const float* __restrict__ W1, bf16* __restrict__ w1kt,
    float* __restrict__ proj_part)
{
    const int blk = blockIdx.x;
    const int t = threadIdx.x;
    if (blk < 1024) {
        __shared__ float part[4][64];
        const int b = blk >> 2;
        const int q4 = blk & 3;              // d-range [512*q4, 512*q4+512) of concat(query,frame)
        const int h = t & 63;
        const int g = t >> 6;                // 4 chunks of 128 d's
        const float* src = (q4 < 2 ? query : frame) + (size_t)b * 1024 + (q4 & 1) * 512 + g * 128;
        const float* wrow = W1 + (size_t)(512 + q4 * 512 + g * 128) * 64 + h;
        float acc = 0.f;
#pragma unroll 8
        for (int dd = 0; dd < 128; dd++)
            acc += src[dd] * wrow[(size_t)dd * 64];
        part[g][h] = acc;
        __syncthreads();
        if (t < 64)
            proj_part[((size_t)q4 * NB + b) * 64 + t] =
                part[0][t] + part[1][t] + part[2][t] + part[3][t];
    } else {
        __shared__ float s[32][65];
        const int j = blk - 1024;            // 0..15
        const int k0 = j * 32;
#pragma unroll
        for (int i = 0; i < 8; i++) {
            const int idx = t + 256 * i;
            const int k = idx >> 6, h = idx & 63;
            s[k][h] = W1[(size_t)(k0 + k) * 64 + h];
        }
        __syncthreads();
#pragma unroll
        for (int i = 0; i < 8; i++) {
            const int idx = t + 256 * i;
            const int h = idx >> 5, kk = idx & 31;
            w1kt[(size_t)h * 512 + k0 + kk] = (bf16)s[kk][h];
        }
    }
}

// ---------------- attn: fused, one block per batch ----------------
__global__ __launch_bounds__(256) void attn_kernel(
    const float* __restrict__ keys, const float* __restrict__ frame,
    const int* __restrict__ mask, const float* __restrict__ W2,
    const bf16* __restrict__ w1kt, const float* __restrict__ proj_part,
    float* __restrict__ out)
{
    extern __shared__ char smem[];
    bf16* sk      = (bf16*)smem;                  // [128][520] bf16
    float* scores = (float*)(smem + SK_BYTES);    // [128]
    float* wts    = scores + 128;                 // [128]
    float* projl  = wts + 128;                    // [64]
    float* w2l    = projl + 64;                   // [64]

    const int b = blockIdx.x;
    const int t = threadIdx.x;

    if (t < 64)
        projl[t] = proj_part[(size_t)b * 64 + t]
                 + proj_part[((size_t)NB + b) * 64 + t]
                 + proj_part[((size_t)2 * NB + b) * 64 + t]
                 + proj_part[((size_t)3 * NB + b) * 64 + t];
    else if (t < 128) w2l[t - 64] = W2[t - 64];

    // ---- stage keys[b] (128x512 fp32) -> LDS bf16; explicit double-buffered
    //      register pipeline: group j+1's 16 loads in flight while cvt+write j.
    const float* kb = keys + (size_t)b * (NP * NK);
    {
        const int rowadd = t >> 7;            // 0/1
        const int c0 = (t & 127) * 4;
        float4 kv[2][16];
#pragma unroll
        for (int ii = 0; ii < 16; ii++)
            kv[0][ii] = *(const float4*)(kb + (size_t)ii * 1024 + t * 4);
#pragma unroll
        for (int jj = 0; jj < 4; jj++) {
            const int cur = jj & 1;
            if (jj < 3) {
#pragma unroll
                for (int ii = 0; ii < 16; ii++)
                    kv[cur ^ 1][ii] =
                        *(const float4*)(kb + (size_t)((jj + 1) * 16 + ii) * 1024 + t * 4);
            }
#pragma unroll
            for (int ii = 0; ii < 16; ii++) {
                const float4 v = kv[cur][ii];
                bf16x4 bv;
                bv[0] = (bf16)v.x; bv[1] = (bf16)v.y;
                bv[2] = (bf16)v.z; bv[3] = (bf16)v.w;
                *(bf16x4*)(sk + (size_t)(2 * (jj * 16 + ii) + rowadd) * SKLD + c0) = bv;
            }
        }
    }
    __syncthreads();

    // ---- GEMM: C[p][h] = keys_bf16 @ W1k_bf16, nt-outer, B double-buffered.
    //      A from LDS (lgkmcnt), B prefetch from L2 (vmcnt) — queues disjoint.
    const int w = t >> 6;
    const int lane = t & 63;
    const int m = lane & 15;       // C col (h within tile)
    const int q = lane >> 4;       // C row = q*4 + r
    const int pw = w * 32;         // wave's p-base (2 M-tiles)

    const bf16* bbase = w1kt + (size_t)m * 512 + q * 8;   // + nt*16*512 + kk*32

    bf16x8 Bv[2][16];
#pragma unroll
    for (int kk = 0; kk < 16; kk++)
        Bv[0][kk] = *(const bf16x8*)(bbase + kk * 32);

    float pr[2][4] = {{0.f,0.f,0.f,0.f},{0.f,0.f,0.f,0.f}};

#pragma unroll
    for (int nt = 0; nt < 4; nt++) {
        const int cur = nt & 1;
        if (nt < 3) {
#pragma unroll
            for (int kk = 0; kk < 16; kk++)
                Bv[cur ^ 1][kk] = *(const bf16x8*)(bbase + (nt + 1) * 8192 + kk * 32);
        }
        f32x4 acc0 = (f32x4){0.f,0.f,0.f,0.f};
        f32x4 acc1 = (f32x4){0.f,0.f,0.f,0.f};
#pragma unroll
        for (int kk = 0; kk < 16; kk++) {
            const int k0 = kk * 32 + q * 8;
            const bf16x8 A0 = *(const bf16x8*)(sk + (pw + m) * SKLD + k0);
            const bf16x8 A1 = *(const bf16x8*)(sk + (pw + 16 + m) * SKLD + k0);
            acc0 = __builtin_amdgcn_mfma_f32_16x16x32_bf16(A0, Bv[cur][kk], acc0, 0, 0, 0);
            acc1 = __builtin_amdgcn_mfma_f32_16x16x32_bf16(A1, Bv[cur][kk], acc1, 0, 0, 0);
        }
        // fold this nt's 16 h-columns into the running score partials
        const int h = nt * 16 + m;
        const float pv = projl[h];
        const float wv = w2l[h];
#pragma unroll
        for (int r = 0; r < 4; r++) {
            pr[0][r] += fmaxf(acc0[r] + pv, 0.f) * wv;
            pr[1][r] += fmaxf(acc1[r] + pv, 0.f) * wv;
        }
    }

    // ---- reduce over the 16 h-lanes, write scores[p] ----
#pragma unroll
    for (int off = 1; off < 16; off <<= 1) {
#pragma unroll
        for (int mt = 0; mt < 2; mt++)
#pragma unroll
            for (int r = 0; r < 4; r++)
                pr[mt][r] += __shfl_xor(pr[mt][r], off);
    }
    if (m == 0) {
#pragma unroll
        for (int mt = 0; mt < 2; mt++) {
            const int pbase = pw + mt * 16 + q * 4;
#pragma unroll
            for (int r = 0; r < 4; r++) scores[pbase + r] = pr[mt][r];
        }
    }
    __syncthreads();

    // ---- masked softmax over 128 scores (wave 0), write weights ----
    if (w == 0) {
        const int pa = lane, pb = lane + 64;
        float s0 = (mask[b * 128 + pa] == 0) ? -INFINITY : scores[pa];
        float s1 = (mask[b * 128 + pb] == 0) ? -INFINITY : scores[pb];
        float mx = fmaxf(s0, s1);
#pragma unroll
        for (int off = 32; off; off >>= 1) mx = fmaxf(mx, __shfl_xor(mx, off));
        float e0 = __expf(s0 - mx), e1 = __expf(s1 - mx);
        float sum = e0 + e1;
#pragma unroll
        for (int off = 32; off; off >>= 1) sum += __shfl_xor(sum, off);
        const float inv = 1.0f / sum;
        e0 *= inv; e1 *= inv;
        wts[pa] = e0; wts[pb] = e1;
        float* wout = out + (size_t)NB * 1536;
        wout[b * 128 + pa] = e0;
        wout[b * 128 + pb] = e1;
    }
    __syncthreads();

    // ---- context[k] = sum_p w[p]*keys[p][k]; thread owns cols 2t, 2t+1 ----
    {
        float a0 = 0.f, a1 = 0.f;
        const int c = 2 * t;
#pragma unroll 8
        for (int p = 0; p < 128; p++) {
            const float wv = wts[p];
            const uint32_t uv = *(const uint32_t*)(sk + p * SKLD + c);
            a0 += wv * __uint_as_float(uv << 16);
            a1 += wv * __uint_as_float(uv & 0xffff0000u);
        }
        out[(size_t)b * 1536 + c] = a0;
        out[(size_t)b * 1536 + c + 1] = a1;
    }
    // ---- frame passthrough: embeddings[:, 512:1536] = frameLSTM_h ----
    {
        const float4 fv = *(const float4*)(frame + (size_t)b * 1024 + t * 4);
        *(float4*)(out + (size_t)b * 1536 + 512 + t * 4) = fv;
    }
}

extern "C" void kernel_launch(void* const* d_in, const int* in_sizes, int n_in,
                              void* d_out, int out_size, void* d_ws, size_t ws_size,
                              hipStream_t stream) {
    const float* query = (const float*)d_in[0];
    const float* keys  = (const float*)d_in[1];
    const float* frame = (const float*)d_in[2];
    const int*   mask  = (const int*)d_in[3];
    const float* W1    = (const float*)d_in[4];
    const float* W2    = (const float*)d_in[5];
    float* out = (float*)d_out;

    // ws: [0,64K) w1kt bf16 [64][512]; [64K,320K) proj_part fp32 [4][256][64]
    bf16*  w1kt      = (bf16*)d_ws;
    float* proj_part = (float*)((char*)d_ws + (64 << 10));

    hipFuncSetAttribute((const void*)attn_kernel,
                        hipFuncAttributeMaxDynamicSharedMemorySize, SMEM_BYTES);

    prep_kernel<<<1040, 256, 0, stream>>>(query, frame, W1, w1kt, proj_part);
    attn_kernel<<<256, 256, SMEM_BYTES, stream>>>(keys, frame, mask, W2, w1kt,
                                                  proj_part, out);
}

// Round 8
// 123.092 us; speedup vs baseline: 1.4622x; 1.0031x over previous
//
#include <hip/hip_runtime.h>
#include <hip/hip_bf16.h>
#include <cstdint>
#include <math.h>

// Shapes: B=256, P=128, K=512, HE=1024, HF=512 (2HF=1024), D=2560, HID=64
// Outputs: embeddings (256,1,1536) then weights (256,128), fp32, flat-concat.
//
// R7: prep = pure repack (w1kt [64][512], w1qft [64][2048], both bf16 K-major).
//     attn = fused, 1 block/batch: (P) proj via broadcast-A MFMA over L2-hot
//     w1qft -> (A) keys staging w/ explicit reg double-buffer -> (G) score
//     MFMA (nt-outer, B double-buffered) -> softmax -> context -> outputs.
// Ledger (attn-path µs): R2 fused 39 | R3 split 44 | R5 interleave 95 |
//     R6 handshake 65 | R7 fused+dbuf 36. prep: GEMV-split4 12 -> repack ~3.
// Lessons: no inter-block coupling; vmcnt is one queue (keep phases
// dependency-homogeneous); pipelines = explicit register arrays.

typedef __bf16 bf16;
typedef __attribute__((ext_vector_type(8))) __bf16 bf16x8;
typedef __attribute__((ext_vector_type(4))) __bf16 bf16x4;
typedef __attribute__((ext_vector_type(4))) float f32x4;

#define NB 256
#define NP 128
#define NK 512
#define SKLD 520   // keys LDS row stride (bf16): 1040B/row -> 2-way bank alias (free)
#define SK_BYTES (NP * SKLD * 2)                  // 133120
// + scores[128] + wts[128] + pp[4][64] + w2l[64]
#define SMEM_BYTES (SK_BYTES + 128*4 + 128*4 + 256*4 + 64*4)  // 135424

// ---------------- prep: weight repack only ----------------
// blocks 0..15 : w1kt[h][k]  = bf16(W1[k*64+h]),        k-rows [32j,32j+32)
// blocks 16..79: w1qft[h][d] = bf16(W1[(512+d)*64+h]),  d-rows [32j,32j+32)
__global__ __launch_bounds__(256) void prep_kernel(
    const float* __restrict__ W1, bf16* __restrict__ w1kt,
    bf16* __restrict__ w1qft)
{
    const int blk = blockIdx.x;
    const int t = threadIdx.x;
    __shared__ float s[32][65];
    if (blk < 16) {
        const int k0 = blk * 32;
#pragma unroll
        for (int i = 0; i < 8; i++) {
            const int idx = t + 256 * i;
            const int k = idx >> 6, h = idx & 63;
            s[k][h] = W1[(size_t)(k0 + k) * 64 + h];
        }
        __syncthreads();
#pragma unroll
        for (int i = 0; i < 8; i++) {
            const int idx = t + 256 * i;
            const int h = idx >> 5, kk = idx & 31;
            w1kt[(size_t)h * 512 + k0 + kk] = (bf16)s[kk][h];
        }
    } else {
        const int j = blk - 16;              // 0..63
        const int d0 = j * 32;
#pragma unroll
        for (int i = 0; i < 8; i++) {
            const int idx = t + 256 * i;
            const int r = idx >> 6, h = idx & 63;
            s[r][h] = W1[(size_t)(512 + d0 + r) * 64 + h];
        }
        __syncthreads();
#pragma unroll
        for (int i = 0; i < 8; i++) {
            const int idx = t + 256 * i;
            const int h = idx >> 5, rr = idx & 31;
            w1qft[(size_t)h * 2048 + d0 + rr] = (bf16)s[rr][h];
        }
    }
}

// ---------------- attn: fused, one block per batch ----------------
__global__ __launch_bounds__(256) void attn_kernel(
    const float* __restrict__ keys, const float* __restrict__ query,
    const float* __restrict__ frame, const int* __restrict__ mask,
    const float* __restrict__ W2, const bf16* __restrict__ w1kt,
    const bf16* __restrict__ w1qft, float* __restrict__ out)
{
    extern __shared__ char smem[];
    bf16* sk      = (bf16*)smem;                  // [128][520] bf16
    float* scores = (float*)(smem + SK_BYTES);    // [128]
    float* wts    = scores + 128;                 // [128]
    float* pp     = wts + 128;                    // [4][64] proj partials
    float* w2l    = pp + 256;                     // [64]

    const int b = blockIdx.x;
    const int t = threadIdx.x;
    const int w = t >> 6;          // wave id
    const int lane = t & 63;
    const int m = lane & 15;
    const int q = lane >> 4;

    if (t < 64) w2l[t] = W2[t];

    // ---- phase P: proj partial for d-chunk [512w, 512w+512) via MFMA ----
    // A = qf broadcast to all 16 rows (C rows identical; read row 0 at q==0),
    // B = w1qft (L2-hot). Short, completes before staging issues (one vmcnt q).
    {
        const float* qf = (w < 2 ? query : frame) + (size_t)b * 1024 + (w & 1) * 512;
        const bf16* wb = w1qft + (size_t)m * 2048 + w * 512 + q * 8;  // +nt*32768 +kk*32
        f32x4 pacc[4];
#pragma unroll
        for (int nt = 0; nt < 4; nt++) pacc[nt] = (f32x4){0.f, 0.f, 0.f, 0.f};

        float4 qa = *(const float4*)(qf + q * 8);
        float4 qb = *(const float4*)(qf + q * 8 + 4);
        bf16x8 Bp[4];
#pragma unroll
        for (int nt = 0; nt < 4; nt++) Bp[nt] = *(const bf16x8*)(wb + nt * 32768);

#pragma unroll
        for (int kk = 0; kk < 16; kk++) {
            bf16x8 Af;
            Af[0] = (bf16)qa.x; Af[1] = (bf16)qa.y; Af[2] = (bf16)qa.z; Af[3] = (bf16)qa.w;
            Af[4] = (bf16)qb.x; Af[5] = (bf16)qb.y; Af[6] = (bf16)qb.z; Af[7] = (bf16)qb.w;
            bf16x8 Bc[4];
#pragma unroll
            for (int nt = 0; nt < 4; nt++) Bc[nt] = Bp[nt];
            if (kk < 15) {
                qa = *(const float4*)(qf + (kk + 1) * 32 + q * 8);
                qb = *(const float4*)(qf + (kk + 1) * 32 + q * 8 + 4);
#pragma unroll
                for (int nt = 0; nt < 4; nt++)
                    Bp[nt] = *(const bf16x8*)(wb + nt * 32768 + (kk + 1) * 32);
            }
#pragma unroll
            for (int nt = 0; nt < 4; nt++)
                pacc[nt] = __builtin_amdgcn_mfma_f32_16x16x32_bf16(Af, Bc[nt], pacc[nt], 0, 0, 0);
        }
        if (q == 0) {
#pragma unroll
            for (int nt = 0; nt < 4; nt++)
                pp[w * 64 + nt * 16 + m] = pacc[nt][0];
        }
    }

    // ---- phase A: stage keys[b] (128x512 fp32) -> LDS bf16; explicit
    //      double-buffered register pipeline (16 loads in flight). ----
    const float* kb = keys + (size_t)b * (NP * NK);
    {
        const int rowadd = t >> 7;            // 0/1
        const int c0 = (t & 127) * 4;
        float4 kv[2][16];
#pragma unroll
        for (int ii = 0; ii < 16; ii++)
            kv[0][ii] = *(const float4*)(kb + (size_t)ii * 1024 + t * 4);
#pragma unroll
        for (int jj = 0; jj < 4; jj++) {
            const int cur = jj & 1;
            if (jj < 3) {
#pragma unroll
                for (int ii = 0; ii < 16; ii++)
                    kv[cur ^ 1][ii] =
                        *(const float4*)(kb + (size_t)((jj + 1) * 16 + ii) * 1024 + t * 4);
            }
#pragma unroll
            for (int ii = 0; ii < 16; ii++) {
                const float4 v = kv[cur][ii];
                bf16x4 bv;
                bv[0] = (bf16)v.x; bv[1] = (bf16)v.y;
                bv[2] = (bf16)v.z; bv[3] = (bf16)v.w;
                *(bf16x4*)(sk + (size_t)(2 * (jj * 16 + ii) + rowadd) * SKLD + c0) = bv;
            }
        }
    }
    __syncthreads();

    // ---- phase G: C[p][h] = keys_bf16 @ W1k_bf16, nt-outer, B double-buffered ----
    const int pw = w * 32;         // wave's p-base (2 M-tiles)
    const bf16* bbase = w1kt + (size_t)m * 512 + q * 8;   // + nt*16*512 + kk*32

    bf16x8 Bv[2][16];
#pragma unroll
    for (int kk = 0; kk < 16; kk++)
        Bv[0][kk] = *(const bf16x8*)(bbase + kk * 32);

    float pr[2][4] = {{0.f,0.f,0.f,0.f},{0.f,0.f,0.f,0.f}};

#pragma unroll
    for (int nt = 0; nt < 4; nt++) {
        const int cur = nt & 1;
        if (nt < 3) {
#pragma unroll
            for (int kk = 0; kk < 16; kk++)
                Bv[cur ^ 1][kk] = *(const bf16x8*)(bbase + (nt + 1) * 8192 + kk * 32);
        }
        f32x4 acc0 = (f32x4){0.f,0.f,0.f,0.f};
        f32x4 acc1 = (f32x4){0.f,0.f,0.f,0.f};
#pragma unroll
        for (int kk = 0; kk < 16; kk++) {
            const int k0 = kk * 32 + q * 8;
            const bf16x8 A0 = *(const bf16x8*)(sk + (pw + m) * SKLD + k0);
            const bf16x8 A1 = *(const bf16x8*)(sk + (pw + 16 + m) * SKLD + k0);
            acc0 = __builtin_amdgcn_mfma_f32_16x16x32_bf16(A0, Bv[cur][kk], acc0, 0, 0, 0);
            acc1 = __builtin_amdgcn_mfma_f32_16x16x32_bf16(A1, Bv[cur][kk], acc1, 0, 0, 0);
        }
        // fold this nt's 16 h-columns into running score partials
        const int h = nt * 16 + m;
        const float pv = pp[h] + pp[64 + h] + pp[128 + h] + pp[192 + h];
        const float wv = w2l[h];
#pragma unroll
        for (int r = 0; r < 4; r++) {
            pr[0][r] += fmaxf(acc0[r] + pv, 0.f) * wv;
            pr[1][r] += fmaxf(acc1[r] + pv, 0.f) * wv;
        }
    }

    // ---- reduce over the 16 h-lanes, write scores[p] ----
#pragma unroll
    for (int off = 1; off < 16; off <<= 1) {
#pragma unroll
        for (int mt = 0; mt < 2; mt++)
#pragma unroll
            for (int r = 0; r < 4; r++)
                pr[mt][r] += __shfl_xor(pr[mt][r], off);
    }
    if (m == 0) {
#pragma unroll
        for (int mt = 0; mt < 2; mt++) {
            const int pbase = pw + mt * 16 + q * 4;
#pragma unroll
            for (int r = 0; r < 4; r++) scores[pbase + r] = pr[mt][r];
        }
    }
    __syncthreads();

    // ---- masked softmax over 128 scores (wave 0), write weights ----
    if (w == 0) {
        const int pa = lane, pb = lane + 64;
        float s0 = (mask[b * 128 + pa] == 0) ? -INFINITY : scores[pa];
        float s1 = (mask[b * 128 + pb] == 0) ? -INFINITY : scores[pb];
        float mx = fmaxf(s0, s1);
#pragma unroll
        for (int off = 32; off; off >>= 1) mx = fmaxf(mx, __shfl_xor(mx, off));
        float e0 = __expf(s0 - mx), e1 = __expf(s1 - mx);
        float sum = e0 + e1;
#pragma unroll
        for (int off = 32; off; off >>= 1) sum += __shfl_xor(sum, off);
        const float inv = 1.0f / sum;
        e0 *= inv; e1 *= inv;
        wts[pa] = e0; wts[pb] = e1;
        float* wout = out + (size_t)NB * 1536;
        wout[b * 128 + pa] = e0;
        wout[b * 128 + pb] = e1;
    }
    __syncthreads();

    // ---- context[k] = sum_p w[p]*keys[p][k]; thread owns cols 2t, 2t+1 ----
    {
        float a0 = 0.f, a1 = 0.f;
        const int c = 2 * t;
#pragma unroll 8
        for (int p = 0; p < 128; p++) {
            const float wv = wts[p];
            const uint32_t uv = *(const uint32_t*)(sk + p * SKLD + c);
            a0 += wv * __uint_as_float(uv << 16);
            a1 += wv * __uint_as_float(uv & 0xffff0000u);
        }
        out[(size_t)b * 1536 + c] = a0;
        out[(size_t)b * 1536 + c + 1] = a1;
    }
    // ---- frame passthrough: embeddings[:, 512:1536] = frameLSTM_h ----
    {
        const float4 fv = *(const float4*)(frame + (size_t)b * 1024 + t * 4);
        *(float4*)(out + (size_t)b * 1536 + 512 + t * 4) = fv;
    }
}

extern "C" void kernel_launch(void* const* d_in, const int* in_sizes, int n_in,
                              void* d_out, int out_size, void* d_ws, size_t ws_size,
                              hipStream_t stream) {
    const float* query = (const float*)d_in[0];
    const float* keys  = (const float*)d_in[1];
    const float* frame = (const float*)d_in[2];
    const int*   mask  = (const int*)d_in[3];
    const float* W1    = (const float*)d_in[4];
    const float* W2    = (const float*)d_in[5];
    float* out = (float*)d_out;

    // ws: [0,64K) w1kt bf16 [64][512]; [64K,320K) w1qft bf16 [64][2048]
    bf16* w1kt  = (bf16*)d_ws;
    bf16* w1qft = (bf16*)((char*)d_ws + (64 << 10));

    hipFuncSetAttribute((const void*)attn_kernel,
                        hipFuncAttributeMaxDynamicSharedMemorySize, SMEM_BYTES);

    prep_kernel<<<80, 256, 0, stream>>>(W1, w1kt, w1qft);
    attn_kernel<<<256, 256, SMEM_BYTES, stream>>>(keys, query, frame, mask, W2,
                                                  w1kt, w1qft, out);
}